// Round 4
// baseline (292.674 us; speedup 1.0000x reference)
//
#include <hip/hip_runtime.h>

// Problem constants (from reference)
#define NNODES 100000
#define NEDGES 3200000
#define DIM    128

typedef __bf16  bf16x8 __attribute__((ext_vector_type(8)));
typedef unsigned short u16;
typedef u16     u16x8  __attribute__((ext_vector_type(8)));
typedef float   f32x4  __attribute__((ext_vector_type(4)));
typedef float   f32x2  __attribute__((ext_vector_type(2)));

__device__ __forceinline__ u16 f2bf(float f) {
    // round-to-nearest-even f32 -> bf16
    union { float f; unsigned int i; } c;
    c.f = f;
    unsigned int x = c.i;
    unsigned int rounding = 0x7fff + ((x >> 16) & 1);
    x += rounding;
    return (u16)(x >> 16);
}

__device__ __forceinline__ float bf2f(u16 u) {
    union { unsigned int i; float f; } c;
    c.i = ((unsigned int)u) << 16;
    return c.f;
}

__device__ __forceinline__ bf16x8 ldfrag_bf(const u16* p) {
    u16x8 u = *(const u16x8*)p;
    return __builtin_bit_cast(bf16x8, u);
}

// load 8 consecutive fp32, convert to bf16x8 fragment (RNE)
__device__ __forceinline__ bf16x8 ldfrag_f32(const float* p) {
    f32x4 a = *(const f32x4*)p;
    f32x4 b = *(const f32x4*)(p + 4);
    u16x8 u;
#pragma unroll
    for (int i = 0; i < 4; ++i) u[i] = f2bf(a[i]);
#pragma unroll
    for (int i = 0; i < 4; ++i) u[4 + i] = f2bf(b[i]);
    return __builtin_bit_cast(bf16x8, u);
}

// ---------------------------------------------------------------------------
// Kernel 1: CSR row_ptr from sorted edge_row via binary search.
// row_ptr[n] = first index i with edge_row[i] >= n, for n in [0, NNODES].
__global__ void build_row_ptr(const int* __restrict__ edge_row,
                              int* __restrict__ row_ptr) {
    int n = blockIdx.x * blockDim.x + threadIdx.x;
    if (n > NNODES) return;
    int lo = 0, hi = NEDGES;
    while (lo < hi) {
        int mid = (lo + hi) >> 1;
        if (edge_row[mid] < n) lo = mid + 1; else hi = mid;
    }
    row_ptr[n] = lo;
}

// ---------------------------------------------------------------------------
// Kernel 2: Wt[n][k] = bf16(W[k][n])  (fp32 -> bf16 transpose, 128x128)
__global__ void prep_wt(const float* __restrict__ w, u16* __restrict__ wt) {
    int i = blockIdx.x * blockDim.x + threadIdx.x;
    if (i >= DIM * DIM) return;
    int k = i >> 7, n = i & 127;
    wt[n * DIM + k] = f2bf(w[k * DIM + n]);
}

// ---------------------------------------------------------------------------
// Kernel 3: y = bf16(x) @ bf16(W)   (fp32 in, bf16 out, fp32 MFMA accumulate)
// Block = 256 threads = 4 waves; each wave computes 16 rows x 128 cols.
// mfma_f32_16x16x32_bf16:
//   A frag: a[j] = A[m = lane&15][k = (lane>>4)*8 + j]   (8 fp32 loads + cvt)
//   B frag: b[j] = B[k = (lane>>4)*8 + j][n = lane&15]   (contiguous in Wt[n][k])
//   C/D:    col = lane&15, row = (lane>>4)*4 + reg       [HW-verified m89]
__global__ __launch_bounds__(256) void gemm_xw(const float* __restrict__ x,
                                               const u16* __restrict__ wt,
                                               u16* __restrict__ y) {
    int wave = __builtin_amdgcn_readfirstlane(threadIdx.x >> 6);
    int lane = threadIdx.x & 63;
    int quad = lane >> 4, l16 = lane & 15;
    int mBase = (blockIdx.x * 4 + wave) * 16;
    if (mBase >= NNODES) return;

    const float* xrow = x + (size_t)(mBase + l16) * DIM + quad * 8;

    f32x4 acc[8];
#pragma unroll
    for (int nt = 0; nt < 8; ++nt) acc[nt] = (f32x4){0.f, 0.f, 0.f, 0.f};

#pragma unroll
    for (int kb = 0; kb < 4; ++kb) {
        bf16x8 a = ldfrag_f32(xrow + kb * 32);
#pragma unroll
        for (int nt = 0; nt < 8; ++nt) {
            bf16x8 b = ldfrag_bf(wt + (nt * 16 + l16) * DIM + kb * 32 + quad * 8);
            acc[nt] = __builtin_amdgcn_mfma_f32_16x16x32_bf16(a, b, acc[nt], 0, 0, 0);
        }
    }

#pragma unroll
    for (int nt = 0; nt < 8; ++nt) {
        int col = nt * 16 + l16;
#pragma unroll
        for (int r = 0; r < 4; ++r) {
            int row = mBase + quad * 4 + r;
            y[(size_t)row * DIM + col] = f2bf(acc[nt][r]);
        }
    }
}

// ---------------------------------------------------------------------------
// Kernel 4: out[n][:] = fp32( bias + sum_{e in row n} val[e] * y[col[e]][:] )
// One wave per node row; lane owns 2 columns (packed bf16x2 = 4B gather, so a
// wave's 64 lanes cover the full 256B y-row coalesced). OUTPUT IS FP32.
__global__ __launch_bounds__(256) void spmm(const int* __restrict__ row_ptr,
                                            const int* __restrict__ ecol,
                                            const float* __restrict__ eval,
                                            const u16* __restrict__ y,
                                            const float* __restrict__ bias,
                                            float* __restrict__ out) {
    int wave = __builtin_amdgcn_readfirstlane(threadIdx.x >> 6);
    int lane = threadIdx.x & 63;
    int row  = blockIdx.x * 4 + wave;
    if (row >= NNODES) return;

    int lo = row_ptr[row];
    int hi = row_ptr[row + 1];

    float acc0 = bias[lane * 2];
    float acc1 = bias[lane * 2 + 1];

    int e = lo;
    for (; e + 4 <= hi; e += 4) {
        int   c0 = ecol[e],     c1 = ecol[e + 1];
        int   c2 = ecol[e + 2], c3 = ecol[e + 3];
        float v0 = eval[e],     v1 = eval[e + 1];
        float v2 = eval[e + 2], v3 = eval[e + 3];
        unsigned int p0 = *(const unsigned int*)(y + (size_t)c0 * DIM + lane * 2);
        unsigned int p1 = *(const unsigned int*)(y + (size_t)c1 * DIM + lane * 2);
        unsigned int p2 = *(const unsigned int*)(y + (size_t)c2 * DIM + lane * 2);
        unsigned int p3 = *(const unsigned int*)(y + (size_t)c3 * DIM + lane * 2);
        acc0 += v0 * bf2f((u16)(p0 & 0xffffu)) + v1 * bf2f((u16)(p1 & 0xffffu))
              + v2 * bf2f((u16)(p2 & 0xffffu)) + v3 * bf2f((u16)(p3 & 0xffffu));
        acc1 += v0 * bf2f((u16)(p0 >> 16))     + v1 * bf2f((u16)(p1 >> 16))
              + v2 * bf2f((u16)(p2 >> 16))     + v3 * bf2f((u16)(p3 >> 16));
    }
    for (; e < hi; ++e) {
        int   c0 = ecol[e];
        float v0 = eval[e];
        unsigned int p0 = *(const unsigned int*)(y + (size_t)c0 * DIM + lane * 2);
        acc0 += v0 * bf2f((u16)(p0 & 0xffffu));
        acc1 += v0 * bf2f((u16)(p0 >> 16));
    }

    f32x2 o; o[0] = acc0; o[1] = acc1;
    *(f32x2*)(out + (size_t)row * DIM + lane * 2) = o;
}

// ---------------------------------------------------------------------------
extern "C" void kernel_launch(void* const* d_in, const int* in_sizes, int n_in,
                              void* d_out, int out_size, void* d_ws, size_t ws_size,
                              hipStream_t stream) {
    const float* x        = (const float*)d_in[0];  // [NNODES, DIM] fp32
    const int*   edge_row = (const int*)d_in[1];    // [NEDGES] int32 (sorted)
    const int*   edge_col = (const int*)d_in[2];    // [NEDGES] int32
    const float* edge_val = (const float*)d_in[3];  // [NEDGES] fp32
    const float* weight   = (const float*)d_in[4];  // [DIM, DIM] fp32
    const float* bias     = (const float*)d_in[5];  // [DIM] fp32
    float* out = (float*)d_out;                     // [NNODES, DIM] fp32

    char* ws = (char*)d_ws;
    // layout: y bf16 [NNODES*DIM] | row_ptr int[NNODES+1] | Wt bf16 [DIM*DIM]
    u16* y       = (u16*)ws;                               // 25,600,000 B
    int* row_ptr = (int*)(ws + (size_t)NNODES * DIM * 2);  // 400,004 B
    u16* wt      = (u16*)(ws + 26000128);                  // 32,768 B (16B aligned)

    // independent prep kernels
    prep_wt<<<(DIM * DIM + 255) / 256, 256, 0, stream>>>(weight, wt);
    build_row_ptr<<<(NNODES + 1 + 255) / 256, 256, 0, stream>>>(edge_row, row_ptr);

    // y = x @ W   : 6250 wave-rows of 16, 4 waves/block -> 1563 blocks
    gemm_xw<<<(NNODES / 16 + 3) / 4, 256, 0, stream>>>(x, wt, y);

    // out = A @ y + bias : one wave per row, 4 waves/block -> 25000 blocks
    spmm<<<NNODES / 4, 256, 0, stream>>>(row_ptr, edge_col, edge_val, y, bias, out);
}

// Round 5
// 276.615 us; speedup vs baseline: 1.0581x; 1.0581x over previous
//
#include <hip/hip_runtime.h>

// Problem constants (from reference)
#define NNODES 100000
#define NEDGES 3200000
#define DIM    128

typedef __bf16  bf16x8 __attribute__((ext_vector_type(8)));
typedef unsigned short u16;
typedef u16     u16x8  __attribute__((ext_vector_type(8)));
typedef float   f32x4  __attribute__((ext_vector_type(4)));
typedef unsigned int u32;
typedef u32     u32x2  __attribute__((ext_vector_type(2)));

__device__ __forceinline__ u16 f2bf(float f) {
    // round-to-nearest-even f32 -> bf16
    union { float f; unsigned int i; } c;
    c.f = f;
    unsigned int x = c.i;
    unsigned int rounding = 0x7fff + ((x >> 16) & 1);
    x += rounding;
    return (u16)(x >> 16);
}

__device__ __forceinline__ float bf2f(u16 u) {
    union { unsigned int i; float f; } c;
    c.i = ((unsigned int)u) << 16;
    return c.f;
}

__device__ __forceinline__ bf16x8 ldfrag_u16(const u16* p) {
    u16x8 u = *(const u16x8*)p;
    return __builtin_bit_cast(bf16x8, u);
}

// load 8 consecutive fp32, convert to bf16x8 fragment (RNE)
__device__ __forceinline__ bf16x8 ldfrag_f32(const float* p) {
    f32x4 a = *(const f32x4*)p;
    f32x4 b = *(const f32x4*)(p + 4);
    u16x8 u;
#pragma unroll
    for (int i = 0; i < 4; ++i) u[i] = f2bf(a[i]);
#pragma unroll
    for (int i = 0; i < 4; ++i) u[4 + i] = f2bf(b[i]);
    return __builtin_bit_cast(bf16x8, u);
}

// ---------------------------------------------------------------------------
// Kernel 1: CSR row_ptr from sorted edge_row via binary search.
__global__ void build_row_ptr(const int* __restrict__ edge_row,
                              int* __restrict__ row_ptr) {
    int n = blockIdx.x * blockDim.x + threadIdx.x;
    if (n > NNODES) return;
    int lo = 0, hi = NEDGES;
    while (lo < hi) {
        int mid = (lo + hi) >> 1;
        if (edge_row[mid] < n) lo = mid + 1; else hi = mid;
    }
    row_ptr[n] = lo;
}

// ---------------------------------------------------------------------------
// Kernel 2: Wt[n][k] = bf16(W[k][n])  (fp32 -> bf16 transpose, 128x128)
__global__ void prep_wt(const float* __restrict__ w, u16* __restrict__ wt) {
    int i = blockIdx.x * blockDim.x + threadIdx.x;
    if (i >= DIM * DIM) return;
    int k = i >> 7, n = i & 127;
    wt[n * DIM + k] = f2bf(w[k * DIM + n]);
}

// ---------------------------------------------------------------------------
// Kernel 3: y = bf16(x) @ bf16(W)  (fp32 in, bf16 out, fp32 MFMA accumulate)
// Wt staged in LDS per block (padded stride 136 u16 -> only 2-way bank
// aliasing on ds_read_b128, which is free). 4 waves/block, 16 rows/wave.
#define WT_STRIDE 136   // u16 units; 272B rows, 16B aligned, breaks pow2 banks
__global__ __launch_bounds__(256) void gemm_xw(const float* __restrict__ x,
                                               const u16* __restrict__ wt,
                                               u16* __restrict__ y) {
    __shared__ u16 wlds[DIM * WT_STRIDE];   // 34816 B

    int tid = threadIdx.x;
    // cooperative staged copy of Wt (128 rows x 256B) into padded LDS
    {
        const f32x4* src = (const f32x4*)wt;   // 16B chunks, 16 per row
#pragma unroll
        for (int i = 0; i < 8; ++i) {
            int ci  = tid + 256 * i;           // 0..2047
            int row = ci >> 4, off = ci & 15;
            *((f32x4*)(wlds + row * WT_STRIDE) + off) = src[ci];
        }
    }
    __syncthreads();

    int wave = __builtin_amdgcn_readfirstlane(tid >> 6);
    int lane = tid & 63;
    int quad = lane >> 4, l16 = lane & 15;
    int mBase = (blockIdx.x * 4 + wave) * 16;
    if (mBase >= NNODES) return;

    const float* xrow = x + (size_t)(mBase + l16) * DIM + quad * 8;

    f32x4 acc[8];
#pragma unroll
    for (int nt = 0; nt < 8; ++nt) acc[nt] = (f32x4){0.f, 0.f, 0.f, 0.f};

#pragma unroll
    for (int kb = 0; kb < 4; ++kb) {
        bf16x8 a = ldfrag_f32(xrow + kb * 32);
#pragma unroll
        for (int nt = 0; nt < 8; ++nt) {
            bf16x8 b = ldfrag_u16(wlds + (nt * 16 + l16) * WT_STRIDE + kb * 32 + quad * 8);
            acc[nt] = __builtin_amdgcn_mfma_f32_16x16x32_bf16(a, b, acc[nt], 0, 0, 0);
        }
    }

#pragma unroll
    for (int nt = 0; nt < 8; ++nt) {
        int col = nt * 16 + l16;
#pragma unroll
        for (int r = 0; r < 4; ++r) {
            int row = mBase + quad * 4 + r;
            y[(size_t)row * DIM + col] = f2bf(acc[nt][r]);
        }
    }
}

// ---------------------------------------------------------------------------
// Kernel 4: out[n][:] = bias + sum_{e in row n} val[e] * y[col[e]][:]
// Half-wave scheme: lanes 0-31 and 32-63 take alternating edges; each lane
// owns 4 columns (8B dwordx2 gather), 4 slots in flight = 8 edges/iter.
// Final __shfl_xor(32) reduce; lanes 0-31 write one coalesced f32x4.
__global__ __launch_bounds__(256) void spmm(const int* __restrict__ row_ptr,
                                            const int* __restrict__ ecol,
                                            const float* __restrict__ eval,
                                            const u16* __restrict__ y,
                                            const float* __restrict__ bias,
                                            float* __restrict__ out) {
    int wave = threadIdx.x >> 6;
    int lane = threadIdx.x & 63;
    int half = lane >> 5;
    int l32  = lane & 31;
    int row  = blockIdx.x * 4 + wave;
    if (row >= NNODES) return;

    int lo = row_ptr[row];
    int hi = row_ptr[row + 1];

    float a0 = 0.f, a1 = 0.f, a2 = 0.f, a3 = 0.f;
    const u16* yb = y + l32 * 4;

    int e = lo;
    for (; e + 8 <= hi; e += 8) {
        int c[4]; float v[4];
#pragma unroll
        for (int s = 0; s < 4; ++s) {
            c[s] = __builtin_nontemporal_load(ecol + e + 2 * s + half);
            v[s] = __builtin_nontemporal_load(eval + e + 2 * s + half);
        }
        u32x2 p[4];
#pragma unroll
        for (int s = 0; s < 4; ++s)
            p[s] = *(const u32x2*)(yb + (size_t)c[s] * DIM);
#pragma unroll
        for (int s = 0; s < 4; ++s) {
            a0 += v[s] * bf2f((u16)(p[s][0] & 0xffffu));
            a1 += v[s] * bf2f((u16)(p[s][0] >> 16));
            a2 += v[s] * bf2f((u16)(p[s][1] & 0xffffu));
            a3 += v[s] * bf2f((u16)(p[s][1] >> 16));
        }
    }
    for (; e + 2 <= hi; e += 2) {
        int   c = __builtin_nontemporal_load(ecol + e + half);
        float v = __builtin_nontemporal_load(eval + e + half);
        u32x2 p = *(const u32x2*)(yb + (size_t)c * DIM);
        a0 += v * bf2f((u16)(p[0] & 0xffffu));
        a1 += v * bf2f((u16)(p[0] >> 16));
        a2 += v * bf2f((u16)(p[1] & 0xffffu));
        a3 += v * bf2f((u16)(p[1] >> 16));
    }
    if (e < hi && half == 0) {
        int   c = ecol[e];
        float v = eval[e];
        u32x2 p = *(const u32x2*)(yb + (size_t)c * DIM);
        a0 += v * bf2f((u16)(p[0] & 0xffffu));
        a1 += v * bf2f((u16)(p[0] >> 16));
        a2 += v * bf2f((u16)(p[1] & 0xffffu));
        a3 += v * bf2f((u16)(p[1] >> 16));
    }

    a0 += __shfl_xor(a0, 32);
    a1 += __shfl_xor(a1, 32);
    a2 += __shfl_xor(a2, 32);
    a3 += __shfl_xor(a3, 32);

    if (half == 0) {
        f32x4 o;
        o[0] = a0 + bias[l32 * 4 + 0];
        o[1] = a1 + bias[l32 * 4 + 1];
        o[2] = a2 + bias[l32 * 4 + 2];
        o[3] = a3 + bias[l32 * 4 + 3];
        __builtin_nontemporal_store(o, (f32x4*)(out + (size_t)row * DIM + l32 * 4));
    }
}

// ---------------------------------------------------------------------------
extern "C" void kernel_launch(void* const* d_in, const int* in_sizes, int n_in,
                              void* d_out, int out_size, void* d_ws, size_t ws_size,
                              hipStream_t stream) {
    const float* x        = (const float*)d_in[0];  // [NNODES, DIM] fp32
    const int*   edge_row = (const int*)d_in[1];    // [NEDGES] int32 (sorted)
    const int*   edge_col = (const int*)d_in[2];    // [NEDGES] int32
    const float* edge_val = (const float*)d_in[3];  // [NEDGES] fp32
    const float* weight   = (const float*)d_in[4];  // [DIM, DIM] fp32
    const float* bias     = (const float*)d_in[5];  // [DIM] fp32
    float* out = (float*)d_out;                     // [NNODES, DIM] fp32

    char* ws = (char*)d_ws;
    // layout: y bf16 [NNODES*DIM] | row_ptr int[NNODES+1] | Wt bf16 [DIM*DIM]
    u16* y       = (u16*)ws;                               // 25,600,000 B
    int* row_ptr = (int*)(ws + (size_t)NNODES * DIM * 2);  // 400,004 B
    u16* wt      = (u16*)(ws + 26000128);                  // 32,768 B (16B aligned)

    prep_wt<<<(DIM * DIM + 255) / 256, 256, 0, stream>>>(weight, wt);
    build_row_ptr<<<(NNODES + 1 + 255) / 256, 256, 0, stream>>>(edge_row, row_ptr);

    // y = x @ W : 6250 wave-rows of 16, 4 waves/block -> 1563 blocks
    gemm_xw<<<(NNODES / 16 + 3) / 4, 256, 0, stream>>>(x, wt, y);

    // out = A @ y + bias : one wave per row, 4 waves/block -> 25000 blocks
    spmm<<<NNODES / 4, 256, 0, stream>>>(row_ptr, edge_col, edge_val, y, bias, out);
}

// Round 6
// 248.792 us; speedup vs baseline: 1.1764x; 1.1118x over previous
//
#include <hip/hip_runtime.h>

// Problem constants (from reference)
#define NNODES 100000
#define NEDGES 3200000
#define DIM    128

typedef __bf16  bf16x8 __attribute__((ext_vector_type(8)));
typedef unsigned short u16;
typedef u16     u16x8  __attribute__((ext_vector_type(8)));
typedef float   f32x4  __attribute__((ext_vector_type(4)));
typedef float   f32x2  __attribute__((ext_vector_type(2)));
typedef unsigned int u32;

__device__ __forceinline__ u16 f2bf(float f) {
    // round-to-nearest-even f32 -> bf16
    union { float f; unsigned int i; } c;
    c.f = f;
    unsigned int x = c.i;
    unsigned int rounding = 0x7fff + ((x >> 16) & 1);
    x += rounding;
    return (u16)(x >> 16);
}

__device__ __forceinline__ float asf(u32 u) {
    union { u32 i; float f; } c; c.i = u; return c.f;
}

__device__ __forceinline__ bf16x8 ldfrag_u16(const u16* p) {
    u16x8 u = *(const u16x8*)p;
    return __builtin_bit_cast(bf16x8, u);
}

// load 8 consecutive fp32, convert to bf16x8 fragment (RNE)
__device__ __forceinline__ bf16x8 ldfrag_f32(const float* p) {
    f32x4 a = *(const f32x4*)p;
    f32x4 b = *(const f32x4*)(p + 4);
    u16x8 u;
#pragma unroll
    for (int i = 0; i < 4; ++i) u[i] = f2bf(a[i]);
#pragma unroll
    for (int i = 0; i < 4; ++i) u[4 + i] = f2bf(b[i]);
    return __builtin_bit_cast(bf16x8, u);
}

// ---------------------------------------------------------------------------
// Kernel 1: CSR row_ptr from sorted edge_row via binary search.
__global__ void build_row_ptr(const int* __restrict__ edge_row,
                              int* __restrict__ row_ptr) {
    int n = blockIdx.x * blockDim.x + threadIdx.x;
    if (n > NNODES) return;
    int lo = 0, hi = NEDGES;
    while (lo < hi) {
        int mid = (lo + hi) >> 1;
        if (edge_row[mid] < n) lo = mid + 1; else hi = mid;
    }
    row_ptr[n] = lo;
}

// ---------------------------------------------------------------------------
// Kernel 2: Wt[n][k] = bf16(W[k][n])  (fp32 -> bf16 transpose, 128x128)
__global__ void prep_wt(const float* __restrict__ w, u16* __restrict__ wt) {
    int i = blockIdx.x * blockDim.x + threadIdx.x;
    if (i >= DIM * DIM) return;
    int k = i >> 7, n = i & 127;
    wt[n * DIM + k] = f2bf(w[k * DIM + n]);
}

// ---------------------------------------------------------------------------
// Kernel 3: y = bf16(x) @ bf16(W)  (fp32 in, bf16 out, fp32 MFMA accumulate)
// Wt staged in LDS per block (padded stride 136 u16 -> 8-per-bank-group on
// ds_read_b128, at the structural b128 floor). 4 waves/block, 16 rows/wave.
// y written through a per-wave LDS bounce tile -> 4x coalesced 1KB stores.
#define WT_STRIDE 136   // u16 units; 272B rows, 16B aligned, breaks pow2 banks
__global__ __launch_bounds__(256) void gemm_xw(const float* __restrict__ x,
                                               const u16* __restrict__ wt,
                                               u16* __restrict__ y) {
    __shared__ u16 wlds[DIM * WT_STRIDE];     // 34816 B
    __shared__ u16 ybounce[4][16 * DIM];      // 4 waves x 4KB = 16384 B

    int tid = threadIdx.x;
    // cooperative staged copy of Wt (128 rows x 256B) into padded LDS
    {
        const f32x4* src = (const f32x4*)wt;   // 16B chunks, 16 per row
#pragma unroll
        for (int i = 0; i < 8; ++i) {
            int ci  = tid + 256 * i;           // 0..2047
            int row = ci >> 4, off = ci & 15;
            *((f32x4*)(wlds + row * WT_STRIDE) + off) = src[ci];
        }
    }
    __syncthreads();

    int wave = __builtin_amdgcn_readfirstlane(tid >> 6);
    int lane = tid & 63;
    int quad = lane >> 4, l16 = lane & 15;
    int mBase = (blockIdx.x * 4 + wave) * 16;
    if (mBase >= NNODES) return;

    const float* xrow = x + (size_t)(mBase + l16) * DIM + quad * 8;

    f32x4 acc[8];
#pragma unroll
    for (int nt = 0; nt < 8; ++nt) acc[nt] = (f32x4){0.f, 0.f, 0.f, 0.f};

#pragma unroll
    for (int kb = 0; kb < 4; ++kb) {
        bf16x8 a = ldfrag_f32(xrow + kb * 32);
#pragma unroll
        for (int nt = 0; nt < 8; ++nt) {
            bf16x8 b = ldfrag_u16(wlds + (nt * 16 + l16) * WT_STRIDE + kb * 32 + quad * 8);
            acc[nt] = __builtin_amdgcn_mfma_f32_16x16x32_bf16(a, b, acc[nt], 0, 0, 0);
        }
    }

    // bounce C-layout -> row-major in per-wave LDS region, then coalesced store
    u16* yb = ybounce[wave];
#pragma unroll
    for (int nt = 0; nt < 8; ++nt) {
        int col = nt * 16 + l16;
#pragma unroll
        for (int r = 0; r < 4; ++r)
            yb[(quad * 4 + r) * DIM + col] = f2bf(acc[nt][r]);
    }
    // per-wave region, in-wave dependency only: compiler inserts lgkmcnt wait
#pragma unroll
    for (int j = 0; j < 4; ++j) {
        int lr = j * 4 + quad;                 // 0..15
        u16x8 t = *(const u16x8*)(yb + lr * DIM + l16 * 8);
        *(u16x8*)(y + (size_t)(mBase + lr) * DIM + l16 * 8) = t;
    }
}

// ---------------------------------------------------------------------------
// Kernel 4: out[n][:] = bias + sum_{e in row n} val[e] * y[col[e]][:]
// One wave per row (row made wave-uniform -> scalar metadata loads).
// Lane owns 2 cols (4B gather => 64 lanes cover the full 256B y-row).
// 8 edges batched -> 8 row-gathers in flight per iteration.
__global__ __launch_bounds__(256) void spmm(const int* __restrict__ row_ptr,
                                            const int* __restrict__ ecol,
                                            const float* __restrict__ eval,
                                            const u16* __restrict__ y,
                                            const float* __restrict__ bias,
                                            float* __restrict__ out) {
    int lane = threadIdx.x & 63;
    int row  = __builtin_amdgcn_readfirstlane(blockIdx.x * 4 + (threadIdx.x >> 6));
    if (row >= NNODES) return;

    int lo = row_ptr[row];
    int hi = row_ptr[row + 1];

    const u16* yl = y + lane * 2;
    float acc0 = 0.f, acc1 = 0.f;

    int e = lo;
    for (; e + 8 <= hi; e += 8) {
        int c[8]; float v[8];
#pragma unroll
        for (int s = 0; s < 8; ++s) { c[s] = ecol[e + s]; v[s] = eval[e + s]; }
        u32 p[8];
#pragma unroll
        for (int s = 0; s < 8; ++s) p[s] = *(const u32*)(yl + (size_t)c[s] * DIM);
#pragma unroll
        for (int s = 0; s < 8; ++s) {
            acc0 += v[s] * asf(p[s] << 16);
            acc1 += v[s] * asf(p[s] & 0xffff0000u);
        }
    }
    for (; e + 4 <= hi; e += 4) {
        int c[4]; float v[4];
#pragma unroll
        for (int s = 0; s < 4; ++s) { c[s] = ecol[e + s]; v[s] = eval[e + s]; }
        u32 p[4];
#pragma unroll
        for (int s = 0; s < 4; ++s) p[s] = *(const u32*)(yl + (size_t)c[s] * DIM);
#pragma unroll
        for (int s = 0; s < 4; ++s) {
            acc0 += v[s] * asf(p[s] << 16);
            acc1 += v[s] * asf(p[s] & 0xffff0000u);
        }
    }
    for (; e < hi; ++e) {
        int   c = ecol[e];
        float v = eval[e];
        u32   p = *(const u32*)(yl + (size_t)c * DIM);
        acc0 += v * asf(p << 16);
        acc1 += v * asf(p & 0xffff0000u);
    }

    f32x2 o;
    o[0] = acc0 + bias[lane * 2];
    o[1] = acc1 + bias[lane * 2 + 1];
    __builtin_nontemporal_store(o, (f32x2*)(out + (size_t)row * DIM + lane * 2));
}

// ---------------------------------------------------------------------------
extern "C" void kernel_launch(void* const* d_in, const int* in_sizes, int n_in,
                              void* d_out, int out_size, void* d_ws, size_t ws_size,
                              hipStream_t stream) {
    const float* x        = (const float*)d_in[0];  // [NNODES, DIM] fp32
    const int*   edge_row = (const int*)d_in[1];    // [NEDGES] int32 (sorted)
    const int*   edge_col = (const int*)d_in[2];    // [NEDGES] int32
    const float* edge_val = (const float*)d_in[3];  // [NEDGES] fp32
    const float* weight   = (const float*)d_in[4];  // [DIM, DIM] fp32
    const float* bias     = (const float*)d_in[5];  // [DIM] fp32
    float* out = (float*)d_out;                     // [NNODES, DIM] fp32

    char* ws = (char*)d_ws;
    // layout: y bf16 [NNODES*DIM] | row_ptr int[NNODES+1] | Wt bf16 [DIM*DIM]
    u16* y       = (u16*)ws;                               // 25,600,000 B
    int* row_ptr = (int*)(ws + (size_t)NNODES * DIM * 2);  // 400,004 B
    u16* wt      = (u16*)(ws + 26000128);                  // 32,768 B (16B aligned)

    prep_wt<<<(DIM * DIM + 255) / 256, 256, 0, stream>>>(weight, wt);
    build_row_ptr<<<(NNODES + 1 + 255) / 256, 256, 0, stream>>>(edge_row, row_ptr);

    // y = x @ W : 6250 wave-rows of 16, 4 waves/block -> 1563 blocks
    gemm_xw<<<(NNODES / 16 + 3) / 4, 256, 0, stream>>>(x, wt, y);

    // out = A @ y + bias : one wave per row, 4 waves/block -> 25000 blocks
    spmm<<<NNODES / 4, 256, 0, stream>>>(row_ptr, edge_col, edge_val, y, bias, out);
}

// Round 7
// 246.065 us; speedup vs baseline: 1.1894x; 1.0111x over previous
//
#include <hip/hip_runtime.h>

// Problem constants (from reference)
#define NNODES 100000
#define NEDGES 3200000
#define DIM    128

typedef __bf16  bf16x8 __attribute__((ext_vector_type(8)));
typedef unsigned short u16;
typedef u16     u16x8  __attribute__((ext_vector_type(8)));
typedef float   f32x4  __attribute__((ext_vector_type(4)));
typedef unsigned int u32;
typedef u32     u32x4  __attribute__((ext_vector_type(4)));

__device__ __forceinline__ u16 f2bf(float f) {
    // round-to-nearest-even f32 -> bf16
    union { float f; unsigned int i; } c;
    c.f = f;
    unsigned int x = c.i;
    unsigned int rounding = 0x7fff + ((x >> 16) & 1);
    x += rounding;
    return (u16)(x >> 16);
}

__device__ __forceinline__ float asf(u32 u) {
    union { u32 i; float f; } c; c.i = u; return c.f;
}

__device__ __forceinline__ bf16x8 ldfrag_u16(const u16* p) {
    u16x8 u = *(const u16x8*)p;
    return __builtin_bit_cast(bf16x8, u);
}

// load 8 consecutive fp32, convert to bf16x8 fragment (RNE)
__device__ __forceinline__ bf16x8 ldfrag_f32(const float* p) {
    f32x4 a = *(const f32x4*)p;
    f32x4 b = *(const f32x4*)(p + 4);
    u16x8 u;
#pragma unroll
    for (int i = 0; i < 4; ++i) u[i] = f2bf(a[i]);
#pragma unroll
    for (int i = 0; i < 4; ++i) u[4 + i] = f2bf(b[i]);
    return __builtin_bit_cast(bf16x8, u);
}

// ---------------------------------------------------------------------------
// Kernel 1: CSR row_ptr from sorted edge_row via binary search.
__global__ void build_row_ptr(const int* __restrict__ edge_row,
                              int* __restrict__ row_ptr) {
    int n = blockIdx.x * blockDim.x + threadIdx.x;
    if (n > NNODES) return;
    int lo = 0, hi = NEDGES;
    while (lo < hi) {
        int mid = (lo + hi) >> 1;
        if (edge_row[mid] < n) lo = mid + 1; else hi = mid;
    }
    row_ptr[n] = lo;
}

// ---------------------------------------------------------------------------
// Kernel 2: Wt[n][k] = bf16(W[k][n])  (fp32 -> bf16 transpose, 128x128)
__global__ void prep_wt(const float* __restrict__ w, u16* __restrict__ wt) {
    int i = blockIdx.x * blockDim.x + threadIdx.x;
    if (i >= DIM * DIM) return;
    int k = i >> 7, n = i & 127;
    wt[n * DIM + k] = f2bf(w[k * DIM + n]);
}

// ---------------------------------------------------------------------------
// Kernel 3: y = bf16(x) @ bf16(W)  (fp32 in, bf16 out, fp32 MFMA accumulate)
// Wt staged in LDS (padded stride 136 u16). 4 waves/block, 16 rows/wave.
// y written through a per-wave LDS bounce tile -> 4x coalesced 1KB stores.
#define WT_STRIDE 136   // u16 units; 272B rows, 16B aligned, breaks pow2 banks
__global__ __launch_bounds__(256) void gemm_xw(const float* __restrict__ x,
                                               const u16* __restrict__ wt,
                                               u16* __restrict__ y) {
    __shared__ u16 wlds[DIM * WT_STRIDE];     // 34816 B
    __shared__ u16 ybounce[4][16 * DIM];      // 4 waves x 4KB = 16384 B

    int tid = threadIdx.x;
    // cooperative staged copy of Wt (128 rows x 256B) into padded LDS
    {
        const f32x4* src = (const f32x4*)wt;   // 16B chunks, 16 per row
#pragma unroll
        for (int i = 0; i < 8; ++i) {
            int ci  = tid + 256 * i;           // 0..2047
            int row = ci >> 4, off = ci & 15;
            *((f32x4*)(wlds + row * WT_STRIDE) + off) = src[ci];
        }
    }
    __syncthreads();

    int wave = __builtin_amdgcn_readfirstlane(tid >> 6);
    int lane = tid & 63;
    int quad = lane >> 4, l16 = lane & 15;
    int mBase = (blockIdx.x * 4 + wave) * 16;
    if (mBase >= NNODES) return;

    const float* xrow = x + (size_t)(mBase + l16) * DIM + quad * 8;

    f32x4 acc[8];
#pragma unroll
    for (int nt = 0; nt < 8; ++nt) acc[nt] = (f32x4){0.f, 0.f, 0.f, 0.f};

#pragma unroll
    for (int kb = 0; kb < 4; ++kb) {
        bf16x8 a = ldfrag_f32(xrow + kb * 32);
#pragma unroll
        for (int nt = 0; nt < 8; ++nt) {
            bf16x8 b = ldfrag_u16(wlds + (nt * 16 + l16) * WT_STRIDE + kb * 32 + quad * 8);
            acc[nt] = __builtin_amdgcn_mfma_f32_16x16x32_bf16(a, b, acc[nt], 0, 0, 0);
        }
    }

    // bounce C-layout -> row-major in per-wave LDS region, then coalesced store
    u16* yb = ybounce[wave];
#pragma unroll
    for (int nt = 0; nt < 8; ++nt) {
        int col = nt * 16 + l16;
#pragma unroll
        for (int r = 0; r < 4; ++r)
            yb[(quad * 4 + r) * DIM + col] = f2bf(acc[nt][r]);
    }
#pragma unroll
    for (int j = 0; j < 4; ++j) {
        int lr = j * 4 + quad;                 // 0..15
        u16x8 t = *(const u16x8*)(yb + lr * DIM + l16 * 8);
        *(u16x8*)(y + (size_t)(mBase + lr) * DIM + l16 * 8) = t;
    }
}

// ---------------------------------------------------------------------------
// Kernel 4: out[n][:] = bias + sum_{e in row n} val[e] * y[col[e]][:]
// One wave per row (wave-uniform row -> scalar metadata loads).
// QUAD-EDGE GATHER: one global_load_dwordx4 fetches 16B chunks of FOUR
// different y-rows (lane l: edge grp=l>>4, chunk sub=l&15) = 1KB/instruction,
// 4x fewer vmem slots than dword-per-edge. Each lane accumulates 8 cols for
// its group's edge subset; __shfl_xor(16|32) tree merges groups at the end.
__global__ __launch_bounds__(256, 8) void spmm(const int* __restrict__ row_ptr,
                                               const int* __restrict__ ecol,
                                               const float* __restrict__ eval,
                                               const u16* __restrict__ y,
                                               const float* __restrict__ bias,
                                               float* __restrict__ out) {
    int lane = threadIdx.x & 63;
    int row  = __builtin_amdgcn_readfirstlane(blockIdx.x * 4 + (threadIdx.x >> 6));
    if (row >= NNODES) return;

    int lo = row_ptr[row];
    int hi = row_ptr[row + 1];

    int grp = lane >> 4;   // which edge of the quad this lane serves
    int sub = lane & 15;   // which 16B chunk of the 256B y-row

    float acc[8];
#pragma unroll
    for (int j = 0; j < 8; ++j) acc[j] = 0.f;

    const u16* ychunk = y + sub * 8;

    int e = lo;
    // main loop: 16 edges per iteration, 4 gather insts of 1KB each
    for (; e + 16 <= hi; e += 16) {
#pragma unroll
        for (int b = 0; b < 4; ++b) {
            int e0 = e + b * 4;
            int   c0 = ecol[e0], c1 = ecol[e0 + 1], c2 = ecol[e0 + 2], c3 = ecol[e0 + 3];
            float v0 = eval[e0], v1 = eval[e0 + 1], v2 = eval[e0 + 2], v3 = eval[e0 + 3];
            int   c = grp < 2 ? (grp == 0 ? c0 : c1) : (grp == 2 ? c2 : c3);
            float v = grp < 2 ? (grp == 0 ? v0 : v1) : (grp == 2 ? v2 : v3);
            u32x4 q = *(const u32x4*)(ychunk + (size_t)c * DIM);
#pragma unroll
            for (int j = 0; j < 4; ++j) {
                acc[2 * j]     += v * asf(q[j] << 16);
                acc[2 * j + 1] += v * asf(q[j] & 0xffff0000u);
            }
        }
    }
    // tail: up to 4 edges per pass, padded with v=0 on the repeated index
    for (; e < hi; e += 4) {
        int rem = hi - e;   // >= 1, uniform
        int i1 = rem > 1 ? e + 1 : e, i2 = rem > 2 ? e + 2 : e, i3 = rem > 3 ? e + 3 : e;
        int   c0 = ecol[e],  c1 = ecol[i1], c2 = ecol[i2], c3 = ecol[i3];
        float v0 = eval[e];
        float v1 = rem > 1 ? eval[i1] : 0.f;
        float v2 = rem > 2 ? eval[i2] : 0.f;
        float v3 = rem > 3 ? eval[i3] : 0.f;
        int   c = grp < 2 ? (grp == 0 ? c0 : c1) : (grp == 2 ? c2 : c3);
        float v = grp < 2 ? (grp == 0 ? v0 : v1) : (grp == 2 ? v2 : v3);
        u32x4 q = *(const u32x4*)(ychunk + (size_t)c * DIM);
#pragma unroll
        for (int j = 0; j < 4; ++j) {
            acc[2 * j]     += v * asf(q[j] << 16);
            acc[2 * j + 1] += v * asf(q[j] & 0xffff0000u);
        }
    }

    // merge the 4 lane-groups (same sub, grp 0..3)
#pragma unroll
    for (int j = 0; j < 8; ++j) {
        acc[j] += __shfl_xor(acc[j], 16);
        acc[j] += __shfl_xor(acc[j], 32);
    }

    if (grp == 0) {
        float* orow = out + (size_t)row * DIM + sub * 8;
        f32x4 o0, o1;
#pragma unroll
        for (int j = 0; j < 4; ++j) {
            o0[j] = acc[j]     + bias[sub * 8 + j];
            o1[j] = acc[4 + j] + bias[sub * 8 + 4 + j];
        }
        __builtin_nontemporal_store(o0, (f32x4*)orow);
        __builtin_nontemporal_store(o1, (f32x4*)(orow + 4));
    }
}

// ---------------------------------------------------------------------------
extern "C" void kernel_launch(void* const* d_in, const int* in_sizes, int n_in,
                              void* d_out, int out_size, void* d_ws, size_t ws_size,
                              hipStream_t stream) {
    const float* x        = (const float*)d_in[0];  // [NNODES, DIM] fp32
    const int*   edge_row = (const int*)d_in[1];    // [NEDGES] int32 (sorted)
    const int*   edge_col = (const int*)d_in[2];    // [NEDGES] int32
    const float* edge_val = (const float*)d_in[3];  // [NEDGES] fp32
    const float* weight   = (const float*)d_in[4];  // [DIM, DIM] fp32
    const float* bias     = (const float*)d_in[5];  // [DIM] fp32
    float* out = (float*)d_out;                     // [NNODES, DIM] fp32

    char* ws = (char*)d_ws;
    // layout: y bf16 [NNODES*DIM] | row_ptr int[NNODES+1] | Wt bf16 [DIM*DIM]
    u16* y       = (u16*)ws;                               // 25,600,000 B
    int* row_ptr = (int*)(ws + (size_t)NNODES * DIM * 2);  // 400,004 B
    u16* wt      = (u16*)(ws + 26000128);                  // 32,768 B (16B aligned)

    prep_wt<<<(DIM * DIM + 255) / 256, 256, 0, stream>>>(weight, wt);
    build_row_ptr<<<(NNODES + 1 + 255) / 256, 256, 0, stream>>>(edge_row, row_ptr);

    // y = x @ W : 6250 wave-rows of 16, 4 waves/block -> 1563 blocks
    gemm_xw<<<(NNODES / 16 + 3) / 4, 256, 0, stream>>>(x, wt, y);

    // out = A @ y + bias : one wave per row, 4 waves/block -> 25000 blocks
    spmm<<<NNODES / 4, 256, 0, stream>>>(row_ptr, edge_col, edge_val, y, bias, out);
}